// Round 1
// 192.624 us; speedup vs baseline: 1.0202x; 1.0202x over previous
//
#include <hip/hip_runtime.h>

// Correlation layer: out[b,o,h,w] = mean_c x1[b,c,h,w] * x2[b,c,h+dh,w+dw]
// B=8 C=128 H=W=128, d=4 -> 81 offsets (o = (dh+4)*9 + (dw+4)).
//
// R3 change vs R2 (91 us/dispatch, VALUBusy 31%, ~3413 cyc/iter):
//  - prefetch ISSUE moved to AFTER __syncthreads(). hipcc drains
//    vmcnt(0) before every s_barrier, so R2's issue-before-barrier
//    pattern exposed a full L3 load latency (~1100 cyc) every channel
//    iteration. With issue-after-barrier, vmcnt is already 0 at the
//    barrier (prev prefetch consumed by the ds_write's data-dep wait)
//    and the new loads fly during the ~1500+ cyc compute phase.

constexpr int Bn = 8, Cn = 128, Hn = 128, Wn = 128;
constexpr int HWn = Hn * Wn;
constexpr int TH = 4;            // output rows per tile
constexpr int NDH = 3;           // dh values per group
constexpr int NR = TH + NDH - 1; // staged x2 rows = 6
constexpr int WP = 144;          // padded LDS row: cols -4..135 at idx 0..139
constexpr int NF4 = (NR * 140) / 4; // 210 float4 staging slots

__global__ __launch_bounds__(256, 3)
void corr_kernel(const float* __restrict__ x1, const float* __restrict__ x2,
                 float* __restrict__ out) {
  __shared__ float s2[2][2][NR][WP];  // [buf][half][row][col]
  __shared__ float sred[128][36];     // cross-half reduction buffer

  const int t    = threadIdx.x;
  const int half = t >> 7;            // 0: c 0..63, 1: c 64..127
  const int q    = t & 127;
  const int row  = q >> 5;            // 0..3 (output row within tile)
  const int w0   = (q & 31) << 2;     // 0,4,...,124

  // --- XCD swizzle: tile's 3 groups + 32 tiles of one batch per XCD ---
  const int phys = blockIdx.x;        // 0..767
  const int xcd  = phys & 7;          // assumed round-robin placement
  const int slot = phys >> 3;         // 0..95
  const int tl   = slot / 3;          // 0..31
  const int g    = slot % 3;          // dh group
  const int tile = xcd * 32 + tl;     // b = tile>>5 == xcd
  const int b    = tile >> 5;
  const int h0   = (tile & 31) * TH;
  const int dhm  = g * NDH - 4;       // first dh of group: -4, -1, +2

  // --- staging slots this thread fills each channel ---
  const int i0 = q, i1 = q + 128;
  const int sr0 = i0 / 35, fc0 = i0 % 35;
  int sr1 = i1 / 35; const int fc1 = i1 % 35;
  const bool act1 = (i1 < NF4);
  if (sr1 > NR - 1) sr1 = NR - 1;     // clamp; store gated by act1
  const int gr0 = h0 + dhm + sr0;
  const int gr1 = h0 + dhm + sr1;
  const bool ok0 = ((unsigned)gr0 < (unsigned)Hn) && (fc0 >= 1) && (fc0 <= 32);
  const bool ok1 = act1 && ((unsigned)gr1 < (unsigned)Hn) && (fc1 >= 1) && (fc1 <= 32);
  const int off0 = gr0 * Wn + fc0 * 4 - 4;  // cols fc*4-4 .. fc*4-1
  const int off1 = gr1 * Wn + fc1 * 4 - 4;

  const float* x1c = x1 + (size_t)b * Cn * HWn + (size_t)(half * 64) * HWn
                        + (h0 + row) * Wn + w0;
  const float* x2c = x2 + (size_t)b * Cn * HWn + (size_t)(half * 64) * HWn;

  float4 acc[NDH][9];
#pragma unroll
  for (int r = 0; r < NDH; ++r)
#pragma unroll
    for (int dw = 0; dw < 9; ++dw) acc[r][dw] = make_float4(0.f, 0.f, 0.f, 0.f);

  // --- prologue: prefetch channel 0 into registers ---
  float4 pv0 = make_float4(0.f, 0.f, 0.f, 0.f);
  float4 pv1 = make_float4(0.f, 0.f, 0.f, 0.f);
  if (ok0) pv0 = *(const float4*)(x2c + off0);
  if (ok1) pv1 = *(const float4*)(x2c + off1);
  float4 pa = *(const float4*)x1c;

#pragma unroll 1
  for (int cc = 0; cc < 64; ++cc) {
    const int buf = cc & 1;
    // write staged channel cc (prefetched last iter; vmcnt wait here is
    // covered by the previous iteration's full compute phase)
    *(float4*)&s2[buf][half][sr0][fc0 * 4] = pv0;
    if (act1) *(float4*)&s2[buf][half][sr1][fc1 * 4] = pv1;
    const float4 a = pa;  // register copy before pa is overwritten below
    __syncthreads();  // vmcnt already 0 here -> barrier drain is ~free;
                      // also separates last iter's reads of buf^1 from
                      // next iter's writes to it
    // issue prefetch for channel cc+1 AFTER the barrier so the compiler's
    // vmcnt(0)-before-s_barrier drain cannot expose its latency; it lands
    // during this iteration's compute, consumed at next iter's ds_write
    if (cc < 63) {
      const float* nx2 = x2c + (size_t)(cc + 1) * HWn;
      if (ok0) pv0 = *(const float4*)(nx2 + off0);
      if (ok1) pv1 = *(const float4*)(nx2 + off1);
      pa = *(const float4*)(x1c + (size_t)(cc + 1) * HWn);
    }

#pragma unroll
    for (int r = 0; r < NDH; ++r) {
      const float* srow = &s2[buf][half][row + r][w0];  // idx w0 == col w0-4
      const float4 wa = *(const float4*)(srow);
      const float4 wb = *(const float4*)(srow + 4);
      const float4 wc = *(const float4*)(srow + 8);
      const float win[12] = {wa.x, wa.y, wa.z, wa.w, wb.x, wb.y, wb.z, wb.w,
                             wc.x, wc.y, wc.z, wc.w};
      // pixel j (j=0..3) with offset dw-4 reads win[j+dw]
#pragma unroll
      for (int dw = 0; dw < 9; ++dw) {
        acc[r][dw].x += a.x * win[dw + 0];
        acc[r][dw].y += a.y * win[dw + 1];
        acc[r][dw].z += a.z * win[dw + 2];
        acc[r][dw].w += a.w * win[dw + 3];
      }
    }
  }

  // --- cross-half reduction + store ---
  const float scale = 1.0f / 128.0f;
  float* ob = out + (size_t)b * 81 * HWn + (size_t)(h0 + row) * Wn + w0;
#pragma unroll
  for (int r = 0; r < NDH; ++r) {
    if (half) {
#pragma unroll
      for (int dw = 0; dw < 9; ++dw) *(float4*)&sred[q][dw * 4] = acc[r][dw];
    }
    __syncthreads();
    if (!half) {
      const int obase = (g * 3 + r) * 9;
#pragma unroll
      for (int dw = 0; dw < 9; ++dw) {
        const float4 s = *(const float4*)&sred[q][dw * 4];
        const float4 m = acc[r][dw];
        float4 rz;
        rz.x = (m.x + s.x) * scale;
        rz.y = (m.y + s.y) * scale;
        rz.z = (m.z + s.z) * scale;
        rz.w = (m.w + s.w) * scale;
        *(float4*)(ob + (size_t)(obase + dw) * HWn) = rz;
      }
    }
    __syncthreads();
  }
}

extern "C" void kernel_launch(void* const* d_in, const int* in_sizes, int n_in,
                              void* d_out, int out_size, void* d_ws, size_t ws_size,
                              hipStream_t stream) {
  const float* x1 = (const float*)d_in[0];
  const float* x2 = (const float*)d_in[1];
  float* out = (float*)d_out;
  const int n_wgs = Bn * (Hn / TH) * 3;  // 768 = 3 per CU
  corr_kernel<<<dim3(n_wgs), dim3(256), 0, stream>>>(x1, x2, out);
}